// Round 8
// baseline (445.727 us; speedup 1.0000x reference)
//
#include <hip/hip_runtime.h>
#include <math.h>

#define B_SZ 2
#define CDIM 256
#define NTOK 4096
#define NH 8
#define HD 32
#define LOG2E 1.44269504088896340736f

typedef __attribute__((ext_vector_type(8))) short short8;
typedef __attribute__((ext_vector_type(4))) float f32x4;

#if __has_builtin(__builtin_amdgcn_exp2f)
#define EXP2F(x) __builtin_amdgcn_exp2f(x)
#else
#define EXP2F(x) exp2f(x)
#endif

static __device__ __forceinline__ unsigned short f2bf(float f) {
    unsigned int u = __builtin_bit_cast(unsigned int, f);
    u = u + 0x7fffu + ((u >> 16) & 1u);
    return (unsigned short)(u >> 16);
}
static __device__ __forceinline__ float bf2f(unsigned short u) {
    unsigned int x = ((unsigned int)u) << 16;
    return __builtin_bit_cast(float, x);
}
// pack two floats -> two bf16 in one u32 (scalar RNE casts; compiler schedules these well)
static __device__ __forceinline__ unsigned int pk2(float a, float b) {
    return (unsigned int)f2bf(a) | ((unsigned int)f2bf(b) << 16);
}

// ------- transpose+bf16: src (B, C, N) fp32 -> dst (B, N, dst_ld) bf16 -------
// Also used for weight transposes (B=1): W (K,N) -> W^T (N,K).
__global__ __launch_bounds__(256) void transpose_bf_kernel(
    const float* __restrict__ src, unsigned short* __restrict__ dst,
    int Cdim, int Ndim, int dst_ld) {
    __shared__ float tile[32][33];
    int tx = threadIdx.x & 31;
    int ty = threadIdx.x >> 5;  // 0..7
    int i0 = blockIdx.x * 32;
    int c0 = blockIdx.y * 32;
    int b = blockIdx.z;
    const float* s = src + (size_t)b * Cdim * Ndim;
    unsigned short* d = dst + (size_t)b * Ndim * dst_ld;
#pragma unroll
    for (int r = 0; r < 4; ++r) {
        int c = c0 + ty + r * 8;
        tile[ty + r * 8][tx] = s[(size_t)c * Ndim + i0 + tx];
    }
    __syncthreads();
#pragma unroll
    for (int r = 0; r < 4; ++r) {
        int i = i0 + ty + r * 8;
        d[(size_t)i * dst_ld + c0 + tx] = f2bf(tile[tx][ty + r * 8]);
    }
}

// ------------- bf16 MFMA GEMM: C[M,N] = (A[M,K](lda) @ BT[N,K]^T + bias) * scale -------------
// A: bf16 row-major (lda). BT: bf16 (N,K) row-major (W^T), ld = K.
// 4 waves/block; wave w computes rows [bx*64+w*16, +16) x cols [by*64, +64).
// OUT_MODE 0: fp32 row-major (ldc). 1: bf16 QKV permute (b,h,n,hd).
// 2: bf16 V^T permute (b,h,hd,n). 3: bf16 row-major (ldc).
template <int RELU, int OUT_MODE>
__global__ __launch_bounds__(256) void bgemm_kernel(
    const unsigned short* __restrict__ A, int lda,
    const unsigned short* __restrict__ BT,
    const float* __restrict__ bias, float scale,
    void* __restrict__ Cv, int ldc, int K) {
    int tid = threadIdx.x;
    int w = tid >> 6;
    int l = tid & 63;
    int lg = l >> 4;   // 0..3
    int lc = l & 15;   // 0..15
    int m0 = blockIdx.x * 64 + w * 16;
    int n0 = blockIdx.y * 64;
    const unsigned short* arow = A + (size_t)(m0 + lc) * lda;
    f32x4 acc[4];
    f32x4 zero = {0.f, 0.f, 0.f, 0.f};
#pragma unroll
    for (int nt = 0; nt < 4; ++nt) acc[nt] = zero;
#pragma unroll 4
    for (int k0 = 0; k0 < K; k0 += 32) {
        short8 af = *(const short8*)&arow[k0 + lg * 8];
#pragma unroll
        for (int nt = 0; nt < 4; ++nt) {
            short8 bf = *(const short8*)&BT[(size_t)(n0 + nt * 16 + lc) * K + k0 + lg * 8];
            acc[nt] = __builtin_amdgcn_mfma_f32_16x16x32_bf16(af, bf, acc[nt], 0, 0, 0);
        }
    }
#pragma unroll
    for (int nt = 0; nt < 4; ++nt) {
#pragma unroll
        for (int r = 0; r < 4; ++r) {
            int m = m0 + lg * 4 + r;
            int n = n0 + nt * 16 + lc;
            float v = acc[nt][r];
            if (bias) v += bias[n];
            v *= scale;
            if (RELU) v = fmaxf(v, 0.f);
            if (OUT_MODE == 0) {
                ((float*)Cv)[(size_t)m * ldc + n] = v;
            } else if (OUT_MODE == 1) {
                int b = m >> 12, itok = m & 4095;
                int h = n >> 5, dd = n & 31;
                ((unsigned short*)Cv)[(((size_t)b * NH + h) * NTOK + itok) * HD + dd] = f2bf(v);
            } else if (OUT_MODE == 2) {
                int b = m >> 12, itok = m & 4095;
                int h = n >> 5, dd = n & 31;
                ((unsigned short*)Cv)[(((size_t)b * NH + h) * HD + dd) * NTOK + itok] = f2bf(v);
            } else {
                ((unsigned short*)Cv)[(size_t)m * ldc + n] = f2bf(v);
            }
        }
    }
}

// ---------------- MFMA flash attention, swapped-operand (bf16 in, fp32 accum) ----------------
// Q (pre-scaled by log2e), K: (b, h, ntok, 32) bf16.  VT: (b, h, 32, ntok) bf16.
// 4 waves/block, wave w owns queries [qt*64 + w*16, +16).
// QK^T computed as mfma(K, Q): D[key=lg*4+r][query=lc] -> per-lane softmax state (query=lc).
// PV computed as O^T = mfma(V^T, P^T): D[d=lg*4+r][query=lc] -> rescale in-lane, no broadcasts.
// merged written bf16 with the faithful head-flatten permute.
__global__ __launch_bounds__(256) void attn_kernel(
    const unsigned short* __restrict__ Q, const unsigned short* __restrict__ K,
    const unsigned short* __restrict__ VT, unsigned short* __restrict__ merged) {
    __shared__ __align__(16) unsigned short Ps[4][2][16][72];  // per-wave, kv-parity dbuf
    int tid = threadIdx.x;
    int w = tid >> 6;
    int l = tid & 63;
    int lg = l >> 4;   // 0..3
    int lc = l & 15;   // 0..15  (this lane's query within the wave's 16)
    int qt = blockIdx.x, h = blockIdx.y, b = blockIdx.z;
    size_t head_off = ((size_t)b * NH + h) * NTOK * HD;
    const unsigned short* Qb = Q + head_off;
    const unsigned short* Kb = K + head_off;
    const unsigned short* Vb = VT + head_off;  // (32, NTOK)

    // Q fragment (B-operand): col=lc -> Q[q][lg*8..+7]
    short8 qf = *(const short8*)&Qb[(size_t)(qt * 64 + w * 16 + lc) * HD + lg * 8];

    f32x4 zero = {0.f, 0.f, 0.f, 0.f};
    f32x4 oacc[2];  // O^T: d = dt*16 + lg*4 + r, q = lc
    oacc[0] = zero;
    oacc[1] = zero;
    float m_run = -3.0e38f, l_run = 0.f;

#pragma unroll 2
    for (int kv = 0; kv < NTOK / 64; ++kv) {
        unsigned short (*ps)[72] = Ps[w][kv & 1];
        // ---- scores (log2 domain, Q pre-scaled): S'[key][q], 4 MFMAs ----
        f32x4 sacc[4];
#pragma unroll
        for (int kt = 0; kt < 4; ++kt) {
            short8 kf = *(const short8*)&Kb[(size_t)(kv * 64 + kt * 16 + lc) * HD + lg * 8];
            sacc[kt] = __builtin_amdgcn_mfma_f32_16x16x32_bf16(kf, qf, zero, 0, 0, 0);
        }
        // ---- per-lane online softmax (16 in-reg keys + cross-lg reduce) ----
        float x0 = fmaxf(fmaxf(sacc[0][0], sacc[0][1]), fmaxf(sacc[0][2], sacc[0][3]));
        float x1 = fmaxf(fmaxf(sacc[1][0], sacc[1][1]), fmaxf(sacc[1][2], sacc[1][3]));
        float x2 = fmaxf(fmaxf(sacc[2][0], sacc[2][1]), fmaxf(sacc[2][2], sacc[2][3]));
        float x3 = fmaxf(fmaxf(sacc[3][0], sacc[3][1]), fmaxf(sacc[3][2], sacc[3][3]));
        float tmax = fmaxf(fmaxf(x0, x1), fmaxf(x2, x3));
        tmax = fmaxf(tmax, __shfl_xor(tmax, 16));
        tmax = fmaxf(tmax, __shfl_xor(tmax, 32));
        float m_new = fmaxf(m_run, tmax);
        float alpha = EXP2F(m_run - m_new);
#pragma unroll
        for (int kt = 0; kt < 4; ++kt)
#pragma unroll
            for (int r = 0; r < 4; ++r)
                sacc[kt][r] = EXP2F(sacc[kt][r] - m_new);
        float s0 = (sacc[0][0] + sacc[0][1]) + (sacc[0][2] + sacc[0][3]);
        float s1 = (sacc[1][0] + sacc[1][1]) + (sacc[1][2] + sacc[1][3]);
        float s2 = (sacc[2][0] + sacc[2][1]) + (sacc[2][2] + sacc[2][3]);
        float s3 = (sacc[3][0] + sacc[3][1]) + (sacc[3][2] + sacc[3][3]);
        float psum = (s0 + s1) + (s2 + s3);
        psum += __shfl_xor(psum, 16);
        psum += __shfl_xor(psum, 32);
        l_run = l_run * alpha + psum;
        m_run = m_new;
        // ---- P -> LDS (packed bf16 pairs): ps[q=lc][key] ----
#pragma unroll
        for (int kt = 0; kt < 4; ++kt) {
            uint2 u = make_uint2(pk2(sacc[kt][0], sacc[kt][1]), pk2(sacc[kt][2], sacc[kt][3]));
            *(uint2*)&ps[lc][kt * 16 + lg * 4] = u;
        }
        // ---- rescale O (per-lane alpha) ----
#pragma unroll
        for (int dt = 0; dt < 2; ++dt)
#pragma unroll
            for (int r = 0; r < 4; ++r)
                oacc[dt][r] *= alpha;
        // ---- PV: O^T[32d x 16q] += V^T[32d x 64k] @ P^T[64k x 16q] ----
#pragma unroll
        for (int ktile = 0; ktile < 2; ++ktile) {
            short8 pf = *(const short8*)&ps[lc][ktile * 32 + lg * 8];
#pragma unroll
            for (int dt = 0; dt < 2; ++dt) {
                short8 vf = *(const short8*)&Vb[(size_t)(dt * 16 + lc) * NTOK + kv * 64 + ktile * 32 + lg * 8];
                oacc[dt] = __builtin_amdgcn_mfma_f32_16x16x32_bf16(vf, pf, oacc[dt], 0, 0, 0);
            }
        }
    }
    // ---- epilogue: merged[b][h*512 + q>>3][(q&7)*32 + d], bf16, packed stores ----
    float inv = 1.f / l_run;
    int q = qt * 64 + w * 16 + lc;
    size_t base = ((size_t)b * NTOK + h * 512 + (q >> 3)) * 256 + (q & 7) * 32;
#pragma unroll
    for (int dt = 0; dt < 2; ++dt) {
        uint2 u = make_uint2(pk2(oacc[dt][0] * inv, oacc[dt][1] * inv),
                             pk2(oacc[dt][2] * inv, oacc[dt][3] * inv));
        *(uint2*)&merged[base + dt * 16 + lg * 4] = u;
    }
}

// ---------------- layernorm over 256, one wave per row ----------------
// OUT_BF16: write bf16 to dst; else fp32. HAS_RESID: add bf16 residual.
template <int OUT_BF16, int HAS_RESID>
__global__ __launch_bounds__(256) void ln_kernel(
    const float* __restrict__ src, int src_ld,
    const float* __restrict__ gamma, const float* __restrict__ beta,
    void* __restrict__ dst, int dst_ld, int dst_off,
    const unsigned short* __restrict__ resid, int resid_ld) {
    int lane = threadIdx.x & 63;
    int wv = threadIdx.x >> 6;
    int row = blockIdx.x * 4 + wv;
    const float* p = src + (size_t)row * src_ld;
    float4 v4 = *(const float4*)&p[lane * 4];
    float vv[4] = {v4.x, v4.y, v4.z, v4.w};
    float sum = vv[0] + vv[1] + vv[2] + vv[3];
#pragma unroll
    for (int off = 32; off >= 1; off >>= 1) sum += __shfl_xor(sum, off);
    float mu = sum * (1.f / 256.f);
    float vs = 0.f;
#pragma unroll
    for (int j = 0; j < 4; ++j) {
        float dxe = vv[j] - mu;
        vs += dxe * dxe;
    }
#pragma unroll
    for (int off = 32; off >= 1; off >>= 1) vs += __shfl_xor(vs, off);
    float rs = rsqrtf(vs * (1.f / 256.f) + 1e-5f);
#pragma unroll
    for (int j = 0; j < 4; ++j) {
        int c = lane * 4 + j;
        float val = (vv[j] - mu) * rs * gamma[c] + beta[c];
        if (HAS_RESID) val += bf2f(resid[(size_t)row * resid_ld + c]);
        if (OUT_BF16)
            ((unsigned short*)dst)[(size_t)row * dst_ld + dst_off + c] = f2bf(val);
        else
            ((float*)dst)[(size_t)row * dst_ld + dst_off + c] = val;
    }
}

extern "C" void kernel_launch(void* const* d_in, const int* in_sizes, int n_in,
                              void* d_out, int out_size, void* d_ws, size_t ws_size,
                              hipStream_t stream) {
    const float* x = (const float*)d_in[0];
    const float* source = (const float*)d_in[1];
    const float* Wq = (const float*)d_in[2];
    const float* bq = (const float*)d_in[3];
    const float* Wk = (const float*)d_in[4];
    const float* bk = (const float*)d_in[5];
    const float* Wv = (const float*)d_in[6];
    const float* bv = (const float*)d_in[7];
    const float* Wm = (const float*)d_in[8];
    const float* Wmlp1 = (const float*)d_in[9];
    const float* Wmlp2 = (const float*)d_in[10];
    const float* g1 = (const float*)d_in[11];
    const float* b1 = (const float*)d_in[12];
    const float* g2 = (const float*)d_in[13];
    const float* b2 = (const float*)d_in[14];
    float* out = (float*)d_out;
    unsigned short* u = (unsigned short*)d_ws;

    // workspace layout (ushort offsets):
    unsigned short* C0bf = u;                 // (2,4096,512) bf16: [:,:,0:256]=xt, [256:512]=a
    unsigned short* stbf = u + 4194304;       // (2,4096,256) bf16
    unsigned short* WqT  = u + 6291456;       // (256,256) bf16 each
    unsigned short* WkT  = u + 6356992;
    unsigned short* WvT  = u + 6422528;
    unsigned short* WmT  = u + 6488064;
    unsigned short* W1T  = u + 6553600;       // (512,512)
    unsigned short* W2T  = u + 6815744;       // (256,512)
    unsigned short* Qb   = u + 6946816;       // (2,8,4096,32) bf16 (pre-scaled by log2e)
    unsigned short* Kb   = u + 9043968;
    unsigned short* Vt   = u + 11141120;      // (2,8,32,4096) bf16
    unsigned short* merged = u + 13238272;    // (2,4096,256) bf16
    float* t1 = (float*)(u + 6946816);        // fp32 (2,4096,256), reuses Qb+Kb after attn
    unsigned short* t2 = u + 11141120;        // bf16 (2,4096,512), reuses Vt+merged after Wm GEMM
    float* t3 = (float*)(u + 15335424);       // fp32 (2,4096,256)

    // 1. activations -> bf16 token-major
    transpose_bf_kernel<<<dim3(128, 8, B_SZ), 256, 0, stream>>>(x, C0bf, 256, 4096, 512);
    transpose_bf_kernel<<<dim3(128, 8, B_SZ), 256, 0, stream>>>(source, stbf, 256, 4096, 256);
    // 2. weights -> bf16 W^T
    transpose_bf_kernel<<<dim3(8, 8, 1), 256, 0, stream>>>(Wq, WqT, 256, 256, 256);
    transpose_bf_kernel<<<dim3(8, 8, 1), 256, 0, stream>>>(Wk, WkT, 256, 256, 256);
    transpose_bf_kernel<<<dim3(8, 8, 1), 256, 0, stream>>>(Wv, WvT, 256, 256, 256);
    transpose_bf_kernel<<<dim3(8, 8, 1), 256, 0, stream>>>(Wm, WmT, 256, 256, 256);
    transpose_bf_kernel<<<dim3(16, 16, 1), 256, 0, stream>>>(Wmlp1, W1T, 512, 512, 512);
    transpose_bf_kernel<<<dim3(8, 16, 1), 256, 0, stream>>>(Wmlp2, W2T, 512, 256, 512);

    // 3. Q/K/V projections (MFMA, bf16 out, head-major; V transposed; Q scaled by log2e)
    dim3 gqkv(128, 4);
    bgemm_kernel<0, 1><<<gqkv, 256, 0, stream>>>(C0bf, 512, WqT, bq, LOG2E, Qb, 0, 256);
    bgemm_kernel<0, 1><<<gqkv, 256, 0, stream>>>(stbf, 256, WkT, bk, 1.0f, Kb, 0, 256);
    bgemm_kernel<0, 2><<<gqkv, 256, 0, stream>>>(stbf, 256, WvT, bv, 1.0f, Vt, 0, 256);

    // 4. MFMA flash attention -> merged bf16 (head-flatten permute)
    attn_kernel<<<dim3(64, NH, B_SZ), 256, 0, stream>>>(Qb, Kb, Vt, merged);

    // 5. merged @ Wm -> t1 fp32
    bgemm_kernel<0, 0><<<gqkv, 256, 0, stream>>>(merged, 256, WmT, nullptr, 1.0f, t1, 256, 256);

    // 6. LN1 -> C0bf upper half (bf16)
    ln_kernel<1, 0><<<2048, 256, 0, stream>>>(t1, 256, g1, b1, C0bf, 512, 256, nullptr, 0);

    // 7. MLP1 + ReLU: C0bf (8192x512) @ W1T -> t2 bf16
    bgemm_kernel<1, 3><<<dim3(128, 8), 256, 0, stream>>>(C0bf, 512, W1T, nullptr, 1.0f, t2, 512, 512);

    // 8. MLP2: t2 @ W2T -> t3 fp32
    bgemm_kernel<0, 0><<<gqkv, 256, 0, stream>>>(t2, 512, W2T, nullptr, 1.0f, t3, 256, 512);

    // 9. LN2 + residual(xt bf16) -> out fp32
    ln_kernel<0, 1><<<2048, 256, 0, stream>>>(t3, 256, g2, b2, out, 256, 0, C0bf, 512);
}

// Round 10
// 337.601 us; speedup vs baseline: 1.3203x; 1.3203x over previous
//
#include <hip/hip_runtime.h>
#include <math.h>

#define B_SZ 2
#define CDIM 256
#define NTOK 4096
#define NH 8
#define HD 32
#define LOG2E 1.44269504088896340736f

typedef __attribute__((ext_vector_type(8))) short short8;
typedef __attribute__((ext_vector_type(4))) float f32x4;

#if __has_builtin(__builtin_amdgcn_exp2f)
#define EXP2F(x) __builtin_amdgcn_exp2f(x)
#else
#define EXP2F(x) exp2f(x)
#endif

static __device__ __forceinline__ unsigned short f2bf(float f) {
    unsigned int u = __builtin_bit_cast(unsigned int, f);
    u = u + 0x7fffu + ((u >> 16) & 1u);
    return (unsigned short)(u >> 16);
}
static __device__ __forceinline__ float bf2f(unsigned short u) {
    unsigned int x = ((unsigned int)u) << 16;
    return __builtin_bit_cast(float, x);
}
static __device__ __forceinline__ unsigned int pk2(float a, float b) {
    return (unsigned int)f2bf(a) | ((unsigned int)f2bf(b) << 16);
}
// async global->LDS, 16B per lane; lds dest must be wave-uniform base (HW adds lane*16)
static __device__ __forceinline__ void gld16(const unsigned short* g, unsigned short* l) {
    __builtin_amdgcn_global_load_lds(
        (const __attribute__((address_space(1))) void*)g,
        (__attribute__((address_space(3))) void*)l, 16, 0, 0);
}

// ------- transpose+bf16: src (B, C, N) fp32 -> dst (B, N, dst_ld) bf16 -------
__global__ __launch_bounds__(256) void transpose_bf_kernel(
    const float* __restrict__ src, unsigned short* __restrict__ dst,
    int Cdim, int Ndim, int dst_ld) {
    __shared__ float tile[32][33];
    int tx = threadIdx.x & 31;
    int ty = threadIdx.x >> 5;
    int i0 = blockIdx.x * 32;
    int c0 = blockIdx.y * 32;
    int b = blockIdx.z;
    const float* s = src + (size_t)b * Cdim * Ndim;
    unsigned short* d = dst + (size_t)b * Ndim * dst_ld;
#pragma unroll
    for (int r = 0; r < 4; ++r) {
        int c = c0 + ty + r * 8;
        tile[ty + r * 8][tx] = s[(size_t)c * Ndim + i0 + tx];
    }
    __syncthreads();
#pragma unroll
    for (int r = 0; r < 4; ++r) {
        int i = i0 + ty + r * 8;
        d[(size_t)i * dst_ld + c0 + tx] = f2bf(tile[tx][ty + r * 8]);
    }
}

// ------------- bf16 MFMA GEMM (unchanged from R8) -------------
template <int RELU, int OUT_MODE>
__global__ __launch_bounds__(256) void bgemm_kernel(
    const unsigned short* __restrict__ A, int lda,
    const unsigned short* __restrict__ BT,
    const float* __restrict__ bias, float scale,
    void* __restrict__ Cv, int ldc, int K) {
    int tid = threadIdx.x;
    int w = tid >> 6;
    int l = tid & 63;
    int lg = l >> 4;
    int lc = l & 15;
    int m0 = blockIdx.x * 64 + w * 16;
    int n0 = blockIdx.y * 64;
    const unsigned short* arow = A + (size_t)(m0 + lc) * lda;
    f32x4 acc[4];
    f32x4 zero = {0.f, 0.f, 0.f, 0.f};
#pragma unroll
    for (int nt = 0; nt < 4; ++nt) acc[nt] = zero;
#pragma unroll 4
    for (int k0 = 0; k0 < K; k0 += 32) {
        short8 af = *(const short8*)&arow[k0 + lg * 8];
#pragma unroll
        for (int nt = 0; nt < 4; ++nt) {
            short8 bf = *(const short8*)&BT[(size_t)(n0 + nt * 16 + lc) * K + k0 + lg * 8];
            acc[nt] = __builtin_amdgcn_mfma_f32_16x16x32_bf16(af, bf, acc[nt], 0, 0, 0);
        }
    }
#pragma unroll
    for (int nt = 0; nt < 4; ++nt) {
#pragma unroll
        for (int r = 0; r < 4; ++r) {
            int m = m0 + lg * 4 + r;
            int n = n0 + nt * 16 + lc;
            float v = acc[nt][r];
            if (bias) v += bias[n];
            v *= scale;
            if (RELU) v = fmaxf(v, 0.f);
            if (OUT_MODE == 0) {
                ((float*)Cv)[(size_t)m * ldc + n] = v;
            } else if (OUT_MODE == 1) {
                int b = m >> 12, itok = m & 4095;
                int h = n >> 5, dd = n & 31;
                ((unsigned short*)Cv)[(((size_t)b * NH + h) * NTOK + itok) * HD + dd] = f2bf(v);
            } else if (OUT_MODE == 2) {
                int b = m >> 12, itok = m & 4095;
                int h = n >> 5, dd = n & 31;
                ((unsigned short*)Cv)[(((size_t)b * NH + h) * HD + dd) * NTOK + itok] = f2bf(v);
            } else {
                ((unsigned short*)Cv)[(size_t)m * ldc + n] = f2bf(v);
            }
        }
    }
}

// ---------------- MFMA flash attention: LDS-staged K/V, 2-phase pipeline ----------------
// Q (pre-scaled by log2e), K: (b,h,ntok,32) bf16. VT: (b,h,32,ntok) bf16.
// 4 waves/block share a double-buffered K/V tile staged via global_load_lds.
// Swizzle (rule #21): linear LDS dest + inverse-swizzled global src + swizzled ds_read.
//   K tile [64 rows][4 granules of 16B]:  granule ^= (row>>1)&3   (2-way banks)
//   V tile [32 rows][8 granules of 16B]:  granule ^= row&7        (2-way banks)
// Softmax identical to R8 (verified): per-lane state, swapped-operand MFMAs.
__global__ __launch_bounds__(256) void attn_kernel(
    const unsigned short* __restrict__ Q, const unsigned short* __restrict__ K,
    const unsigned short* __restrict__ VT, unsigned short* __restrict__ merged) {
    __shared__ __align__(16) unsigned short Kt[2][2048];  // [buf][64*32]
    __shared__ __align__(16) unsigned short Vt[2][2048];  // [buf][32*64]
    __shared__ __align__(16) unsigned short Ps[4][16][72];
    int tid = threadIdx.x;
    int w = tid >> 6;
    int l = tid & 63;
    int lg = l >> 4;
    int lc = l & 15;
    int qt = blockIdx.x, h = blockIdx.y, b = blockIdx.z;
    size_t head_off = ((size_t)b * NH + h) * NTOK * HD;
    const unsigned short* Qb = Q + head_off;
    const unsigned short* Kb = K + head_off;
    const unsigned short* Vb = VT + head_off;  // (32, NTOK)

    short8 qf = *(const short8*)&Qb[(size_t)(qt * 64 + w * 16 + lc) * HD + lg * 8];

    // per-lane pre-swizzled staging sources (16B granules)
    int krow = tid >> 2, kgr = tid & 3;
    const unsigned short* Ks0 = Kb + (size_t)krow * HD + (size_t)(kgr ^ ((krow >> 1) & 3)) * 8;
    int vrow = tid >> 3, vgr = tid & 7;
    const unsigned short* Vs0 = Vb + (size_t)vrow * NTOK + (size_t)(vgr ^ (vrow & 7)) * 8;
    int kxor = (lc >> 1) & 3;  // read-side swizzle for K
    int vxor = lc & 7;         // read-side swizzle for V

    f32x4 zero = {0.f, 0.f, 0.f, 0.f};
    f32x4 oacc[2];
    oacc[0] = zero;
    oacc[1] = zero;
    float m_run = -3.0e38f, l_run = 0.f;

    // prologue: stage tile 0 into buf 0 (drained by the barrier)
    gld16(Ks0, &Kt[0][w * 512]);
    gld16(Vs0, &Vt[0][w * 512]);
    __syncthreads();

    for (int kv = 0; kv < NTOK / 64; ++kv) {
        int cur = kv & 1;
        // issue next tile's staging first; it flies under this tile's compute
        if (kv + 1 < NTOK / 64) {
            gld16(Ks0 + (size_t)(kv + 1) * 64 * HD, &Kt[cur ^ 1][w * 512]);
            gld16(Vs0 + (size_t)(kv + 1) * 64, &Vt[cur ^ 1][w * 512]);
        }
        const unsigned short* Kl = Kt[cur];
        const unsigned short* Vl = Vt[cur];
        // ---- scores (log2 domain): S'[key][q], 4 MFMAs, K frags from LDS ----
        f32x4 sacc[4];
#pragma unroll
        for (int kt = 0; kt < 4; ++kt) {
            short8 kf = *(const short8*)&Kl[(kt * 16 + lc) * 32 + (lg ^ kxor) * 8];
            sacc[kt] = __builtin_amdgcn_mfma_f32_16x16x32_bf16(kf, qf, zero, 0, 0, 0);
        }
        // ---- per-lane online softmax ----
        float x0 = fmaxf(fmaxf(sacc[0][0], sacc[0][1]), fmaxf(sacc[0][2], sacc[0][3]));
        float x1 = fmaxf(fmaxf(sacc[1][0], sacc[1][1]), fmaxf(sacc[1][2], sacc[1][3]));
        float x2 = fmaxf(fmaxf(sacc[2][0], sacc[2][1]), fmaxf(sacc[2][2], sacc[2][3]));
        float x3 = fmaxf(fmaxf(sacc[3][0], sacc[3][1]), fmaxf(sacc[3][2], sacc[3][3]));
        float tmax = fmaxf(fmaxf(x0, x1), fmaxf(x2, x3));
        tmax = fmaxf(tmax, __shfl_xor(tmax, 16));
        tmax = fmaxf(tmax, __shfl_xor(tmax, 32));
        float m_new = fmaxf(m_run, tmax);
        float alpha = EXP2F(m_run - m_new);
#pragma unroll
        for (int kt = 0; kt < 4; ++kt)
#pragma unroll
            for (int r = 0; r < 4; ++r)
                sacc[kt][r] = EXP2F(sacc[kt][r] - m_new);
        float s0 = (sacc[0][0] + sacc[0][1]) + (sacc[0][2] + sacc[0][3]);
        float s1 = (sacc[1][0] + sacc[1][1]) + (sacc[1][2] + sacc[1][3]);
        float s2 = (sacc[2][0] + sacc[2][1]) + (sacc[2][2] + sacc[2][3]);
        float s3 = (sacc[3][0] + sacc[3][1]) + (sacc[3][2] + sacc[3][3]);
        float psum = (s0 + s1) + (s2 + s3);
        psum += __shfl_xor(psum, 16);
        psum += __shfl_xor(psum, 32);
        l_run = l_run * alpha + psum;
        m_run = m_new;
        // ---- P -> LDS (packed bf16 pairs): Ps[w][q=lc][key] ----
#pragma unroll
        for (int kt = 0; kt < 4; ++kt) {
            uint2 u = make_uint2(pk2(sacc[kt][0], sacc[kt][1]), pk2(sacc[kt][2], sacc[kt][3]));
            *(uint2*)&Ps[w][lc][kt * 16 + lg * 4] = u;
        }
        // ---- rescale O ----
#pragma unroll
        for (int dt = 0; dt < 2; ++dt)
#pragma unroll
            for (int r = 0; r < 4; ++r)
                oacc[dt][r] *= alpha;
        // ---- PV: O^T += V^T @ P^T, V frags from LDS ----
#pragma unroll
        for (int ktile = 0; ktile < 2; ++ktile) {
            short8 pf = *(const short8*)&Ps[w][lc][ktile * 32 + lg * 8];
#pragma unroll
            for (int dt = 0; dt < 2; ++dt) {
                short8 vf = *(const short8*)&Vl[(dt * 16 + lc) * 64 + ((ktile * 4 + lg) ^ vxor) * 8];
                oacc[dt] = __builtin_amdgcn_mfma_f32_16x16x32_bf16(vf, pf, oacc[dt], 0, 0, 0);
            }
        }
        // one barrier per iter: drains staging loads (compiler emits vmcnt(0) before s_barrier)
        __syncthreads();
    }
    // ---- epilogue: merged[b][h*512 + q>>3][(q&7)*32 + d], bf16 ----
    float inv = 1.f / l_run;
    int q = qt * 64 + w * 16 + lc;
    size_t base = ((size_t)b * NTOK + h * 512 + (q >> 3)) * 256 + (q & 7) * 32;
#pragma unroll
    for (int dt = 0; dt < 2; ++dt) {
        uint2 u = make_uint2(pk2(oacc[dt][0] * inv, oacc[dt][1] * inv),
                             pk2(oacc[dt][2] * inv, oacc[dt][3] * inv));
        *(uint2*)&merged[base + dt * 16 + lg * 4] = u;
    }
}

// ---------------- layernorm over 256, one wave per row ----------------
template <int OUT_BF16, int HAS_RESID>
__global__ __launch_bounds__(256) void ln_kernel(
    const float* __restrict__ src, int src_ld,
    const float* __restrict__ gamma, const float* __restrict__ beta,
    void* __restrict__ dst, int dst_ld, int dst_off,
    const unsigned short* __restrict__ resid, int resid_ld) {
    int lane = threadIdx.x & 63;
    int wv = threadIdx.x >> 6;
    int row = blockIdx.x * 4 + wv;
    const float* p = src + (size_t)row * src_ld;
    float4 v4 = *(const float4*)&p[lane * 4];
    float vv[4] = {v4.x, v4.y, v4.z, v4.w};
    float sum = vv[0] + vv[1] + vv[2] + vv[3];
#pragma unroll
    for (int off = 32; off >= 1; off >>= 1) sum += __shfl_xor(sum, off);
    float mu = sum * (1.f / 256.f);
    float vs = 0.f;
#pragma unroll
    for (int j = 0; j < 4; ++j) {
        float dxe = vv[j] - mu;
        vs += dxe * dxe;
    }
#pragma unroll
    for (int off = 32; off >= 1; off >>= 1) vs += __shfl_xor(vs, off);
    float rs = rsqrtf(vs * (1.f / 256.f) + 1e-5f);
#pragma unroll
    for (int j = 0; j < 4; ++j) {
        int c = lane * 4 + j;
        float val = (vv[j] - mu) * rs * gamma[c] + beta[c];
        if (HAS_RESID) val += bf2f(resid[(size_t)row * resid_ld + c]);
        if (OUT_BF16)
            ((unsigned short*)dst)[(size_t)row * dst_ld + dst_off + c] = f2bf(val);
        else
            ((float*)dst)[(size_t)row * dst_ld + dst_off + c] = val;
    }
}

extern "C" void kernel_launch(void* const* d_in, const int* in_sizes, int n_in,
                              void* d_out, int out_size, void* d_ws, size_t ws_size,
                              hipStream_t stream) {
    const float* x = (const float*)d_in[0];
    const float* source = (const float*)d_in[1];
    const float* Wq = (const float*)d_in[2];
    const float* bq = (const float*)d_in[3];
    const float* Wk = (const float*)d_in[4];
    const float* bk = (const float*)d_in[5];
    const float* Wv = (const float*)d_in[6];
    const float* bv = (const float*)d_in[7];
    const float* Wm = (const float*)d_in[8];
    const float* Wmlp1 = (const float*)d_in[9];
    const float* Wmlp2 = (const float*)d_in[10];
    const float* g1 = (const float*)d_in[11];
    const float* b1 = (const float*)d_in[12];
    const float* g2 = (const float*)d_in[13];
    const float* b2 = (const float*)d_in[14];
    float* out = (float*)d_out;
    unsigned short* u = (unsigned short*)d_ws;

    // workspace layout (ushort offsets):
    unsigned short* C0bf = u;                 // (2,4096,512) bf16: [:,:,0:256]=xt, [256:512]=a
    unsigned short* stbf = u + 4194304;       // (2,4096,256) bf16
    unsigned short* WqT  = u + 6291456;       // (256,256) bf16 each
    unsigned short* WkT  = u + 6356992;
    unsigned short* WvT  = u + 6422528;
    unsigned short* WmT  = u + 6488064;
    unsigned short* W1T  = u + 6553600;       // (512,512)
    unsigned short* W2T  = u + 6815744;       // (256,512)
    unsigned short* Qb   = u + 6946816;       // (2,8,4096,32) bf16 (pre-scaled by log2e)
    unsigned short* Kb   = u + 9043968;
    unsigned short* Vt   = u + 11141120;      // (2,8,32,4096) bf16
    unsigned short* merged = u + 13238272;    // (2,4096,256) bf16
    float* t1 = (float*)(u + 6946816);        // fp32 (2,4096,256), reuses Qb+Kb after attn
    unsigned short* t2 = u + 11141120;        // bf16 (2,4096,512), reuses Vt+merged after Wm GEMM
    float* t3 = (float*)(u + 15335424);       // fp32 (2,4096,256)

    // 1. activations -> bf16 token-major
    transpose_bf_kernel<<<dim3(128, 8, B_SZ), 256, 0, stream>>>(x, C0bf, 256, 4096, 512);
    transpose_bf_kernel<<<dim3(128, 8, B_SZ), 256, 0, stream>>>(source, stbf, 256, 4096, 256);
    // 2. weights -> bf16 W^T
    transpose_bf_kernel<<<dim3(8, 8, 1), 256, 0, stream>>>(Wq, WqT, 256, 256, 256);
    transpose_bf_kernel<<<dim3(8, 8, 1), 256, 0, stream>>>(Wk, WkT, 256, 256, 256);
    transpose_bf_kernel<<<dim3(8, 8, 1), 256, 0, stream>>>(Wv, WvT, 256, 256, 256);
    transpose_bf_kernel<<<dim3(8, 8, 1), 256, 0, stream>>>(Wm, WmT, 256, 256, 256);
    transpose_bf_kernel<<<dim3(16, 16, 1), 256, 0, stream>>>(Wmlp1, W1T, 512, 512, 512);
    transpose_bf_kernel<<<dim3(8, 16, 1), 256, 0, stream>>>(Wmlp2, W2T, 512, 256, 512);

    // 3. Q/K/V projections (MFMA; Q scaled by log2e; V transposed)
    dim3 gqkv(128, 4);
    bgemm_kernel<0, 1><<<gqkv, 256, 0, stream>>>(C0bf, 512, WqT, bq, LOG2E, Qb, 0, 256);
    bgemm_kernel<0, 1><<<gqkv, 256, 0, stream>>>(stbf, 256, WkT, bk, 1.0f, Kb, 0, 256);
    bgemm_kernel<0, 2><<<gqkv, 256, 0, stream>>>(stbf, 256, WvT, bv, 1.0f, Vt, 0, 256);

    // 4. MFMA flash attention (LDS-staged, 2-phase) -> merged bf16
    attn_kernel<<<dim3(64, NH, B_SZ), 256, 0, stream>>>(Qb, Kb, Vt, merged);

    // 5. merged @ Wm -> t1 fp32
    bgemm_kernel<0, 0><<<gqkv, 256, 0, stream>>>(merged, 256, WmT, nullptr, 1.0f, t1, 256, 256);

    // 6. LN1 -> C0bf upper half (bf16)
    ln_kernel<1, 0><<<2048, 256, 0, stream>>>(t1, 256, g1, b1, C0bf, 512, 256, nullptr, 0);

    // 7. MLP1 + ReLU: C0bf (8192x512) @ W1T -> t2 bf16
    bgemm_kernel<1, 3><<<dim3(128, 8), 256, 0, stream>>>(C0bf, 512, W1T, nullptr, 1.0f, t2, 512, 512);

    // 8. MLP2: t2 @ W2T -> t3 fp32
    bgemm_kernel<0, 0><<<gqkv, 256, 0, stream>>>(t2, 512, W2T, nullptr, 1.0f, t3, 256, 512);

    // 9. LN2 + residual(xt bf16) -> out fp32
    ln_kernel<0, 1><<<2048, 256, 0, stream>>>(t3, 256, g2, b2, out, 256, 0, C0bf, 512);
}

// Round 16
// 259.755 us; speedup vs baseline: 1.7160x; 1.2997x over previous
//
#include <hip/hip_runtime.h>
#include <math.h>

#define B_SZ 2
#define CDIM 256
#define NTOK 4096
#define NH 8
#define HD 32
#define LOG2E 1.44269504088896340736f

typedef __attribute__((ext_vector_type(8))) short short8;
typedef __attribute__((ext_vector_type(4))) float f32x4;

#if __has_builtin(__builtin_amdgcn_exp2f)
#define EXP2F(x) __builtin_amdgcn_exp2f(x)
#else
#define EXP2F(x) exp2f(x)
#endif

static __device__ __forceinline__ unsigned short f2bf(float f) {
    unsigned int u = __builtin_bit_cast(unsigned int, f);
    u = u + 0x7fffu + ((u >> 16) & 1u);
    return (unsigned short)(u >> 16);
}
static __device__ __forceinline__ float bf2f(unsigned short u) {
    unsigned int x = ((unsigned int)u) << 16;
    return __builtin_bit_cast(float, x);
}
static __device__ __forceinline__ unsigned int pk2(float a, float b) {
    return (unsigned int)f2bf(a) | ((unsigned int)f2bf(b) << 16);
}
// async global->LDS, 16B per lane; lds dest is wave-uniform base (HW adds lane*16)
static __device__ __forceinline__ void gld16(const unsigned short* g, unsigned short* l) {
    __builtin_amdgcn_global_load_lds(
        (const __attribute__((address_space(1))) void*)g,
        (__attribute__((address_space(3))) void*)l, 16, 0, 0);
}
// explicit drain of outstanding global_load_lds + LDS ops before a barrier.
// The 2-phase buffer handoff REQUIRES vmcnt(0) before s_barrier; do not rely
// on the compiler's implicit drain (post-timing divergence in R15 = the race).
static __device__ __forceinline__ void drain_mem() {
    asm volatile("s_waitcnt vmcnt(0) lgkmcnt(0)" ::: "memory");
}

// ------- fused activation transposes: z = tensor*2 + batch -------
// x (2,256,4096) -> C0bf (2,4096,512) cols 0..255 ; source -> stbf (2,4096,256)
__global__ __launch_bounds__(256) void transpose_acts_kernel(
    const float* __restrict__ x, const float* __restrict__ source,
    unsigned short* __restrict__ C0bf, unsigned short* __restrict__ stbf) {
    __shared__ float tile[32][33];
    int z = blockIdx.z;
    int b = z & 1, t = z >> 1;
    const float* s = (t ? source : x) + (size_t)b * CDIM * NTOK;
    int ld = t ? 256 : 512;
    unsigned short* d = (t ? stbf : C0bf) + (size_t)b * NTOK * ld;
    int tx = threadIdx.x & 31;
    int ty = threadIdx.x >> 5;
    int i0 = blockIdx.x * 32;
    int c0 = blockIdx.y * 32;
#pragma unroll
    for (int r = 0; r < 4; ++r) {
        int c = c0 + ty + r * 8;
        tile[ty + r * 8][tx] = s[(size_t)c * NTOK + i0 + tx];
    }
    __syncthreads();
#pragma unroll
    for (int r = 0; r < 4; ++r) {
        int i = i0 + ty + r * 8;
        d[(size_t)i * ld + c0 + tx] = f2bf(tile[tx][ty + r * 8]);
    }
}

// ------- fused weight transposes: z selects weight; W (K,N) -> W^T (N,K) bf16 -------
__global__ __launch_bounds__(256) void transpose_w_kernel(
    const float* __restrict__ Wq, const float* __restrict__ Wk, const float* __restrict__ Wv,
    const float* __restrict__ Wm, const float* __restrict__ W1, const float* __restrict__ W2,
    unsigned short* __restrict__ WqT, unsigned short* __restrict__ WkT, unsigned short* __restrict__ WvT,
    unsigned short* __restrict__ WmT, unsigned short* __restrict__ W1T, unsigned short* __restrict__ W2T) {
    __shared__ float tile[32][33];
    int z = blockIdx.z;
    const float* s;
    unsigned short* d;
    int Cdim, Ndim;
    switch (z) {
        case 0: s = Wq; d = WqT; Cdim = 256; Ndim = 256; break;
        case 1: s = Wk; d = WkT; Cdim = 256; Ndim = 256; break;
        case 2: s = Wv; d = WvT; Cdim = 256; Ndim = 256; break;
        case 3: s = Wm; d = WmT; Cdim = 256; Ndim = 256; break;
        case 4: s = W1; d = W1T; Cdim = 512; Ndim = 512; break;
        default: s = W2; d = W2T; Cdim = 512; Ndim = 256; break;
    }
    int i0 = blockIdx.x * 32;  // n
    int c0 = blockIdx.y * 32;  // k
    if (i0 >= Ndim || c0 >= Cdim) return;  // block-uniform, before any barrier
    int tx = threadIdx.x & 31;
    int ty = threadIdx.x >> 5;
#pragma unroll
    for (int r = 0; r < 4; ++r) {
        int c = c0 + ty + r * 8;
        tile[ty + r * 8][tx] = s[(size_t)c * Ndim + i0 + tx];
    }
    __syncthreads();
#pragma unroll
    for (int r = 0; r < 4; ++r) {
        int i = i0 + ty + r * 8;
        d[(size_t)i * Cdim + c0 + tx] = f2bf(tile[tx][ty + r * 8]);
    }
}

// ------------- bf16 MFMA GEMM with LDS-staged B (2-phase gld16 pipeline) -------------
// C[M,N] = (A[M,K](lda) @ BT[N,K]^T) * scale, optional bias/ReLU.
// Block: 256 threads, tile (64*RG) x 64; wave w owns rows [bx*64*RG + w*16*RG, +16*RG).
// B tile [64 n][32 k] staged per k-step; swizzle: granule ^= (row>>1)&3 (both sides, rule #21).
// Explicit drain_mem() before every barrier = buffer-handoff correctness.
// OUT_MODE 0: fp32 row-major. 3: bf16 row-major.
template <int RELU, int OUT_MODE, int RG>
__global__ __launch_bounds__(256) void bgemm_kernel(
    const unsigned short* __restrict__ A, int lda,
    const unsigned short* __restrict__ BT,
    const float* __restrict__ bias, float scale,
    void* __restrict__ Cv, int ldc, int K) {
    __shared__ __align__(16) unsigned short Bs[2][2048];  // [buf][64 x 32]
    int tid = threadIdx.x;
    int w = tid >> 6, l = tid & 63, lg = l >> 4, lc = l & 15;
    int m0 = blockIdx.x * (64 * RG) + w * (16 * RG);
    int n0 = blockIdx.y * 64;
    int brow = tid >> 2, bgr = tid & 3;
    const unsigned short* Bsrc = BT + (size_t)(n0 + brow) * K + (size_t)(bgr ^ ((brow >> 1) & 3)) * 8;
    int bxor = (lc >> 1) & 3;
    const unsigned short* arow[RG];
#pragma unroll
    for (int rg = 0; rg < RG; ++rg) arow[rg] = A + (size_t)(m0 + rg * 16 + lc) * lda;
    f32x4 acc[RG][4];
    f32x4 zero = {0.f, 0.f, 0.f, 0.f};
#pragma unroll
    for (int rg = 0; rg < RG; ++rg)
#pragma unroll
        for (int nt = 0; nt < 4; ++nt) acc[rg][nt] = zero;
    gld16(Bsrc, &Bs[0][w * 512]);
    drain_mem();
    __syncthreads();
    int nsteps = K / 32;
    for (int s = 0; s < nsteps; ++s) {
        int cur = s & 1;
        if (s + 1 < nsteps) gld16(Bsrc + (s + 1) * 32, &Bs[cur ^ 1][w * 512]);
        short8 af[RG];
#pragma unroll
        for (int rg = 0; rg < RG; ++rg) af[rg] = *(const short8*)&arow[rg][s * 32 + lg * 8];
#pragma unroll
        for (int nt = 0; nt < 4; ++nt) {
            short8 bf = *(const short8*)&Bs[cur][(nt * 16 + lc) * 32 + (lg ^ bxor) * 8];
#pragma unroll
            for (int rg = 0; rg < RG; ++rg)
                acc[rg][nt] = __builtin_amdgcn_mfma_f32_16x16x32_bf16(af[rg], bf, acc[rg][nt], 0, 0, 0);
        }
        drain_mem();
        __syncthreads();
    }
#pragma unroll
    for (int rg = 0; rg < RG; ++rg)
#pragma unroll
        for (int nt = 0; nt < 4; ++nt)
#pragma unroll
            for (int r = 0; r < 4; ++r) {
                int m = m0 + rg * 16 + lg * 4 + r;
                int n = n0 + nt * 16 + lc;
                float v = acc[rg][nt][r];
                if (bias) v += bias[n];
                v *= scale;
                if (RELU) v = fmaxf(v, 0.f);
                if (OUT_MODE == 0)
                    ((float*)Cv)[(size_t)m * ldc + n] = v;
                else
                    ((unsigned short*)Cv)[(size_t)m * ldc + n] = f2bf(v);
            }
}

// ------------- fused Q/K/V projection: blockIdx.z selects which -------------
// z=0: C0bf @ WqT *log2e +bq -> Qb (b,h,n,hd);  z=1: stbf @ WkT +bk -> Kb;
// z=2: stbf @ WvT +bv -> Vt (b,h,hd,n).  RG=2 tile (128x64), staged B.
__global__ __launch_bounds__(256) void qkv_kernel(
    const unsigned short* __restrict__ C0bf, const unsigned short* __restrict__ stbf,
    const unsigned short* __restrict__ WqT, const unsigned short* __restrict__ WkT,
    const unsigned short* __restrict__ WvT,
    const float* __restrict__ bq, const float* __restrict__ bk, const float* __restrict__ bv,
    unsigned short* __restrict__ Qb, unsigned short* __restrict__ Kb, unsigned short* __restrict__ Vt) {
    __shared__ __align__(16) unsigned short Bs[2][2048];
    const int K = 256;
    int z = blockIdx.z;
    const unsigned short* A = (z == 0) ? C0bf : stbf;
    int lda = (z == 0) ? 512 : 256;
    const unsigned short* BT = (z == 0) ? WqT : (z == 1) ? WkT : WvT;
    const float* bias = (z == 0) ? bq : (z == 1) ? bk : bv;
    float scale = (z == 0) ? LOG2E : 1.0f;
    unsigned short* outp = (z == 0) ? Qb : (z == 1) ? Kb : Vt;
    int tid = threadIdx.x;
    int w = tid >> 6, l = tid & 63, lg = l >> 4, lc = l & 15;
    int m0 = blockIdx.x * 128 + w * 32;
    int n0 = blockIdx.y * 64;
    int brow = tid >> 2, bgr = tid & 3;
    const unsigned short* Bsrc = BT + (size_t)(n0 + brow) * K + (size_t)(bgr ^ ((brow >> 1) & 3)) * 8;
    int bxor = (lc >> 1) & 3;
    const unsigned short* arow0 = A + (size_t)(m0 + lc) * lda;
    const unsigned short* arow1 = A + (size_t)(m0 + 16 + lc) * lda;
    f32x4 acc[2][4];
    f32x4 zero = {0.f, 0.f, 0.f, 0.f};
#pragma unroll
    for (int rg = 0; rg < 2; ++rg)
#pragma unroll
        for (int nt = 0; nt < 4; ++nt) acc[rg][nt] = zero;
    gld16(Bsrc, &Bs[0][w * 512]);
    drain_mem();
    __syncthreads();
    for (int s = 0; s < K / 32; ++s) {
        int cur = s & 1;
        if (s + 1 < K / 32) gld16(Bsrc + (s + 1) * 32, &Bs[cur ^ 1][w * 512]);
        short8 af0 = *(const short8*)&arow0[s * 32 + lg * 8];
        short8 af1 = *(const short8*)&arow1[s * 32 + lg * 8];
#pragma unroll
        for (int nt = 0; nt < 4; ++nt) {
            short8 bf = *(const short8*)&Bs[cur][(nt * 16 + lc) * 32 + (lg ^ bxor) * 8];
            acc[0][nt] = __builtin_amdgcn_mfma_f32_16x16x32_bf16(af0, bf, acc[0][nt], 0, 0, 0);
            acc[1][nt] = __builtin_amdgcn_mfma_f32_16x16x32_bf16(af1, bf, acc[1][nt], 0, 0, 0);
        }
        drain_mem();
        __syncthreads();
    }
#pragma unroll
    for (int rg = 0; rg < 2; ++rg)
#pragma unroll
        for (int nt = 0; nt < 4; ++nt)
#pragma unroll
            for (int r = 0; r < 4; ++r) {
                int m = m0 + rg * 16 + lg * 4 + r;
                int n = n0 + nt * 16 + lc;
                float v = (acc[rg][nt][r] + bias[n]) * scale;
                int b = m >> 12, itok = m & 4095;
                int h = n >> 5, dd = n & 31;
                size_t idx = (z == 2) ? ((((size_t)b * NH + h) * HD + dd) * NTOK + itok)
                                      : ((((size_t)b * NH + h) * NTOK + itok) * HD + dd);
                outp[idx] = f2bf(v);
            }
}

// ---------------- MFMA flash attention: LDS-staged K/V + defer-max ----------------
__global__ __launch_bounds__(256) void attn_kernel(
    const unsigned short* __restrict__ Q, const unsigned short* __restrict__ K,
    const unsigned short* __restrict__ VT, unsigned short* __restrict__ merged) {
    __shared__ __align__(16) unsigned short Kt[2][2048];  // [buf][64*32]
    __shared__ __align__(16) unsigned short Vt[2][2048];  // [buf][32*64]
    __shared__ __align__(16) unsigned short Ps[4][16][72];
    int tid = threadIdx.x;
    int w = tid >> 6;
    int l = tid & 63;
    int lg = l >> 4;
    int lc = l & 15;
    int qt = blockIdx.x, h = blockIdx.y, b = blockIdx.z;
    size_t head_off = ((size_t)b * NH + h) * NTOK * HD;
    const unsigned short* Qb = Q + head_off;
    const unsigned short* Kb = K + head_off;
    const unsigned short* Vb = VT + head_off;  // (32, NTOK)

    short8 qf = *(const short8*)&Qb[(size_t)(qt * 64 + w * 16 + lc) * HD + lg * 8];

    int krow = tid >> 2, kgr = tid & 3;
    const unsigned short* Ks0 = Kb + (size_t)krow * HD + (size_t)(kgr ^ ((krow >> 1) & 3)) * 8;
    int vrow = tid >> 3, vgr = tid & 7;
    const unsigned short* Vs0 = Vb + (size_t)vrow * NTOK + (size_t)(vgr ^ (vrow & 7)) * 8;
    int kxor = (lc >> 1) & 3;
    int vxor = lc & 7;

    f32x4 zero = {0.f, 0.f, 0.f, 0.f};
    f32x4 oacc[2];
    oacc[0] = zero;
    oacc[1] = zero;
    float m_run = -3.0e38f, l_run = 0.f;

    gld16(Ks0, &Kt[0][w * 512]);
    gld16(Vs0, &Vt[0][w * 512]);
    drain_mem();
    __syncthreads();

    for (int kv = 0; kv < NTOK / 64; ++kv) {
        int cur = kv & 1;
        if (kv + 1 < NTOK / 64) {
            gld16(Ks0 + (size_t)(kv + 1) * 64 * HD, &Kt[cur ^ 1][w * 512]);
            gld16(Vs0 + (size_t)(kv + 1) * 64, &Vt[cur ^ 1][w * 512]);
        }
        const unsigned short* Kl = Kt[cur];
        const unsigned short* Vl = Vt[cur];
        f32x4 sacc[4];
#pragma unroll
        for (int kt = 0; kt < 4; ++kt) {
            short8 kf = *(const short8*)&Kl[(kt * 16 + lc) * 32 + (lg ^ kxor) * 8];
            sacc[kt] = __builtin_amdgcn_mfma_f32_16x16x32_bf16(kf, qf, zero, 0, 0, 0);
        }
        // ---- per-lane online softmax with defer-max (T13, THR=8 in log2 domain) ----
        float x0 = fmaxf(fmaxf(sacc[0][0], sacc[0][1]), fmaxf(sacc[0][2], sacc[0][3]));
        float x1 = fmaxf(fmaxf(sacc[1][0], sacc[1][1]), fmaxf(sacc[1][2], sacc[1][3]));
        float x2 = fmaxf(fmaxf(sacc[2][0], sacc[2][1]), fmaxf(sacc[2][2], sacc[2][3]));
        float x3 = fmaxf(fmaxf(sacc[3][0], sacc[3][1]), fmaxf(sacc[3][2], sacc[3][3]));
        float tmax = fmaxf(fmaxf(x0, x1), fmaxf(x2, x3));
        tmax = fmaxf(tmax, __shfl_xor(tmax, 16));
        tmax = fmaxf(tmax, __shfl_xor(tmax, 32));
        if (!__all(tmax <= m_run + 8.f)) {
            float m_new = fmaxf(m_run, tmax);
            float alpha = EXP2F(m_run - m_new);
            l_run *= alpha;
#pragma unroll
            for (int dt = 0; dt < 2; ++dt)
#pragma unroll
                for (int r = 0; r < 4; ++r)
                    oacc[dt][r] *= alpha;
            m_run = m_new;
        }
#pragma unroll
        for (int kt = 0; kt < 4; ++kt)
#pragma unroll
            for (int r = 0; r < 4; ++r)
                sacc[kt][r] = EXP2F(sacc[kt][r] - m_run);  // bounded by 2^8
        float s0 = (sacc[0][0] + sacc[0][1]) + (sacc[0][2] + sacc[0][3]);
        float s1 = (sacc[1][0] + sacc[1][1]) + (sacc[1][2] + sacc[1][3]);
        float s2 = (sacc[2][0] + sacc[2][1]) + (sacc[2][2] + sacc[2][3]);
        float s3 = (sacc[3][0] + sacc[3][1]) + (sacc[3][2] + sacc[3][3]);
        float psum = (s0 + s1) + (s2 + s3);
        psum += __shfl_xor(psum, 16);
        psum += __shfl_xor(psum, 32);
        l_run += psum;
        // ---- P -> LDS (packed bf16 pairs): Ps[w][q=lc][key] ----
#pragma unroll
        for (int kt = 0; kt < 4; ++kt) {
            uint2 u = make_uint2(pk2(sacc[kt][0], sacc[kt][1]), pk2(sacc[kt][2], sacc[kt][3]));
            *(uint2*)&Ps[w][lc][kt * 16 + lg * 4] = u;
        }
        // ---- PV: O^T += V^T @ P^T ----
#pragma unroll
        for (int ktile = 0; ktile < 2; ++ktile) {
            short8 pf = *(const short8*)&Ps[w][lc][ktile * 32 + lg * 8];
#pragma unroll
            for (int dt = 0; dt < 2; ++dt) {
                short8 vf = *(const short8*)&Vl[(dt * 16 + lc) * 64 + ((ktile * 4 + lg) ^ vxor) * 8];
                oacc[dt] = __builtin_amdgcn_mfma_f32_16x16x32_bf16(vf, pf, oacc[dt], 0, 0, 0);
            }
        }
        drain_mem();
        __syncthreads();
    }
    float inv = 1.f / l_run;
    int q = qt * 64 + w * 16 + lc;
    size_t base = ((size_t)b * NTOK + h * 512 + (q >> 3)) * 256 + (q & 7) * 32;
#pragma unroll
    for (int dt = 0; dt < 2; ++dt) {
        uint2 u = make_uint2(pk2(oacc[dt][0] * inv, oacc[dt][1] * inv),
                             pk2(oacc[dt][2] * inv, oacc[dt][3] * inv));
        *(uint2*)&merged[base + dt * 16 + lg * 4] = u;
    }
}

// ---------------- layernorm over 256, one wave per row ----------------
template <int OUT_BF16, int HAS_RESID>
__global__ __launch_bounds__(256) void ln_kernel(
    const float* __restrict__ src, int src_ld,
    const float* __restrict__ gamma, const float* __restrict__ beta,
    void* __restrict__ dst, int dst_ld, int dst_off,
    const unsigned short* __restrict__ resid, int resid_ld) {
    int lane = threadIdx.x & 63;
    int wv = threadIdx.x >> 6;
    int row = blockIdx.x * 4 + wv;
    const float* p = src + (size_t)row * src_ld;
    float4 v4 = *(const float4*)&p[lane * 4];
    float vv[4] = {v4.x, v4.y, v4.z, v4.w};
    float sum = vv[0] + vv[1] + vv[2] + vv[3];
#pragma unroll
    for (int off = 32; off >= 1; off >>= 1) sum += __shfl_xor(sum, off);
    float mu = sum * (1.f / 256.f);
    float vs = 0.f;
#pragma unroll
    for (int j = 0; j < 4; ++j) {
        float dxe = vv[j] - mu;
        vs += dxe * dxe;
    }
#pragma unroll
    for (int off = 32; off >= 1; off >>= 1) vs += __shfl_xor(vs, off);
    float rs = rsqrtf(vs * (1.f / 256.f) + 1e-5f);
#pragma unroll
    for (int j = 0; j < 4; ++j) {
        int c = lane * 4 + j;
        float val = (vv[j] - mu) * rs * gamma[c] + beta[c];
        if (HAS_RESID) val += bf2f(resid[(size_t)row * resid_ld + c]);
        if (OUT_BF16)
            ((unsigned short*)dst)[(size_t)row * dst_ld + dst_off + c] = f2bf(val);
        else
            ((float*)dst)[(size_t)row * dst_ld + dst_off + c] = val;
    }
}

extern "C" void kernel_launch(void* const* d_in, const int* in_sizes, int n_in,
                              void* d_out, int out_size, void* d_ws, size_t ws_size,
                              hipStream_t stream) {
    const float* x = (const float*)d_in[0];
    const float* source = (const float*)d_in[1];
    const float* Wq = (const float*)d_in[2];
    const float* bq = (const float*)d_in[3];
    const float* Wk = (const float*)d_in[4];
    const float* bk = (const float*)d_in[5];
    const float* Wv = (const float*)d_in[6];
    const float* bv = (const float*)d_in[7];
    const float* Wm = (const float*)d_in[8];
    const float* Wmlp1 = (const float*)d_in[9];
    const float* Wmlp2 = (const float*)d_in[10];
    const float* g1 = (const float*)d_in[11];
    const float* b1 = (const float*)d_in[12];
    const float* g2 = (const float*)d_in[13];
    const float* b2 = (const float*)d_in[14];
    float* out = (float*)d_out;
    unsigned short* u = (unsigned short*)d_ws;

    // workspace layout (ushort offsets):
    unsigned short* C0bf = u;                 // (2,4096,512) bf16: [:,:,0:256]=xt, [256:512]=a
    unsigned short* stbf = u + 4194304;       // (2,4096,256) bf16
    unsigned short* WqT  = u + 6291456;       // (256,256) bf16 each
    unsigned short* WkT  = u + 6356992;
    unsigned short* WvT  = u + 6422528;
    unsigned short* WmT  = u + 6488064;
    unsigned short* W1T  = u + 6553600;       // (512,512)
    unsigned short* W2T  = u + 6815744;       // (256,512)
    unsigned short* Qb   = u + 6946816;       // (2,8,4096,32) bf16 (pre-scaled by log2e)
    unsigned short* Kb   = u + 9043968;
    unsigned short* Vt   = u + 11141120;      // (2,8,32,4096) bf16
    unsigned short* merged = u + 13238272;    // (2,4096,256) bf16
    float* t1 = (float*)(u + 6946816);        // fp32 (2,4096,256), reuses Qb+Kb after attn
    unsigned short* t2 = u + 11141120;        // bf16 (2,4096,512), reuses Vt+merged after Wm GEMM
    float* t3 = (float*)(u + 15335424);       // fp32 (2,4096,256)

    // 1. activations -> bf16 token-major (x and source fused; z = tensor*2 + batch)
    transpose_acts_kernel<<<dim3(128, 8, 4), 256, 0, stream>>>(x, source, C0bf, stbf);
    // 2. all 6 weight transposes in one launch
    transpose_w_kernel<<<dim3(16, 16, 6), 256, 0, stream>>>(
        Wq, Wk, Wv, Wm, Wmlp1, Wmlp2, WqT, WkT, WvT, WmT, W1T, W2T);
    // 3. fused Q/K/V projections (staged-B; Q scaled by log2e; V transposed)
    qkv_kernel<<<dim3(64, 4, 3), 256, 0, stream>>>(C0bf, stbf, WqT, WkT, WvT, bq, bk, bv, Qb, Kb, Vt);
    // 4. MFMA flash attention (LDS-staged, defer-max) -> merged bf16
    attn_kernel<<<dim3(64, NH, B_SZ), 256, 0, stream>>>(Qb, Kb, Vt, merged);
    // 5. merged @ Wm -> t1 fp32 (staged-B)
    bgemm_kernel<0, 0, 1><<<dim3(128, 4), 256, 0, stream>>>(merged, 256, WmT, nullptr, 1.0f, t1, 256, 256);
    // 6. LN1 -> C0bf upper half (bf16)
    ln_kernel<1, 0><<<2048, 256, 0, stream>>>(t1, 256, g1, b1, C0bf, 512, 256, nullptr, 0);
    // 7. MLP1 + ReLU: C0bf (8192x512) @ W1T -> t2 bf16 (staged-B, 128-row tile)
    bgemm_kernel<1, 3, 2><<<dim3(64, 8), 256, 0, stream>>>(C0bf, 512, W1T, nullptr, 1.0f, t2, 512, 512);
    // 8. MLP2: t2 @ W2T -> t3 fp32 (staged-B)
    bgemm_kernel<0, 0, 1><<<dim3(128, 4), 256, 0, stream>>>(t2, 512, W2T, nullptr, 1.0f, t3, 256, 512);
    // 9. LN2 + residual(xt bf16) -> out fp32
    ln_kernel<0, 1><<<2048, 256, 0, stream>>>(t3, 256, g2, b2, out, 256, 0, C0bf, 512);
}